// Round 14
// baseline (162.867 us; speedup 1.0000x reference)
//
#include <hip/hip_runtime.h>

// ---- constants -------------------------------------------------------------
#define BATCH 4
#define SEQ   1024
#define KENC  512
#define HDIM  1024
#define NHEAD 16
#define HD    64
#define LOG2E 1.44269504088896340736f

typedef __attribute__((ext_vector_type(8))) short bf16x8;
typedef __attribute__((ext_vector_type(4))) float f32x4;
typedef __attribute__((ext_vector_type(16))) float f32x16;
typedef __attribute__((ext_vector_type(4))) float f4v;
typedef __attribute__((ext_vector_type(4))) short s4v;

__device__ __forceinline__ short f2bf(float f) {
  unsigned u = __float_as_uint(f);
  u += 0x7fffu + ((u >> 16) & 1u);   // RNE
  return (short)(u >> 16);
}

__device__ __forceinline__ void gload_lds16(const void* g, void* l) {
  __builtin_amdgcn_global_load_lds(
      (const __attribute__((address_space(1))) void*)g,
      (__attribute__((address_space(3))) void*)l, 16, 0, 0);
}

__device__ __forceinline__ float tmax16(const f32x16& v) {
  float a0 = fmaxf(v[0], v[1]),   a1 = fmaxf(v[2], v[3]);
  float a2 = fmaxf(v[4], v[5]),   a3 = fmaxf(v[6], v[7]);
  float a4 = fmaxf(v[8], v[9]),   a5 = fmaxf(v[10], v[11]);
  float a6 = fmaxf(v[12], v[13]), a7 = fmaxf(v[14], v[15]);
  float b0 = fmaxf(a0, a1), b1 = fmaxf(a2, a3);
  float b2 = fmaxf(a4, a5), b3 = fmaxf(a6, a7);
  return fmaxf(fmaxf(b0, b1), fmaxf(b2, b3));
}
__device__ __forceinline__ float tsum16(const f32x16& v) {
  float a0 = v[0] + v[1],   a1 = v[2] + v[3];
  float a2 = v[4] + v[5],   a3 = v[6] + v[7];
  float a4 = v[8] + v[9],   a5 = v[10] + v[11];
  float a6 = v[12] + v[13], a7 = v[14] + v[15];
  float b0 = a0 + a1, b1 = a2 + a3, b2 = a4 + a5, b3 = a6 + a7;
  return (b0 + b1) + (b2 + b3);
}

#define MF(A, B, C) __builtin_amdgcn_mfma_f32_16x16x32_bf16((A), (B), (C), 0, 0, 0)

// ---- kernel 1: fused prep — weight cast+transpose AND activation casts -----
struct PrepArgs { const float* W[6]; };

__global__ __launch_bounds__(256) void prep(PrepArgs a, short* __restrict__ wt,
                                            const float* __restrict__ hid,
                                            short* __restrict__ hbf, int n4h,
                                            const float* __restrict__ enc,
                                            short* __restrict__ ebf, int n4e) {
  __shared__ float t[32][33];
  int blk = blockIdx.x;
  if (blk < 6144) {
    int j = blk >> 10;
    int r = blk & 1023;
    int cb = (r & 31) * 32, rb = (r >> 5) * 32;
    const float* W = a.W[j];
    short* dst = wt + (size_t)j * (HDIM * HDIM);
    int tx = threadIdx.x & 31, ty = threadIdx.x >> 5;
#pragma unroll
    for (int rr = 0; rr < 4; ++rr)
      t[ty + rr * 8][tx] = W[(size_t)(rb + ty + rr * 8) * HDIM + cb + tx];
    __syncthreads();
#pragma unroll
    for (int rr = 0; rr < 4; ++rr)
      dst[(size_t)(cb + ty + rr * 8) * HDIM + rb + tx] = f2bf(t[tx][ty + rr * 8]);
  } else {
    int i = (blk - 6144) * 256 + threadIdx.x;
    const float* s;
    short* d;
    int j;
    if (i < n4h) { s = hid; d = hbf; j = i; }
    else { j = i - n4h; if (j >= n4e) return; s = enc; d = ebf; }
    f4v v = ((const f4v*)s)[j];
    s4v o;
#pragma unroll
    for (int k = 0; k < 4; ++k) o[k] = f2bf(v[k]);
    ((s4v*)d)[j] = o;
  }
}

// ---- kernel 3: projection GEMM — 256x256 tile, 8-wave, 8-phase port --------
// BK=64, 2 K-tile slots per operand (128KB LDS), 4 pinned phases per K-tile:
// {ds-read subtile; barrier; lgkmcnt(0); setprio + 16 MFMA; barrier}.
// Rotation: group h phase-0-top stages tile h+1 -> slot (h+1)&1 (reader of
// that slot finished at the barrier just passed -> no WAR race); vmcnt(8)
// certifies tile h (issued 8 phases earlier). Counted, never 0 in main loop.
struct ProjArgs {
  const short* X[6];
  const short* Wt[6];
  const float* bias[6];
  short* out[6];
  int tshift[6];
  int mode[6];
  float scale[6];
};

__global__ __launch_bounds__(512) void proj_gemm8(ProjArgs a) {
  int id = blockIdx.x;
  int job, bm, bn;
  if (id < 256) { job = id >> 6; int r = id & 63; bm = r >> 2; bn = r & 3; }
  else { int u = id - 256; job = 4 + (u >> 5); int r = u & 31; bm = r >> 2; bn = r & 3; }

  const char* Xb = (const char*)a.X[job];
  const char* Wb = (const char*)a.Wt[job];

  __shared__ __align__(16) char Lds[131072];  // A: 2x32KB @0, B: 2x32KB @64KB

  int tid = threadIdx.x, lane = tid & 63, wave = tid >> 6;
  int wr = wave >> 2, wc = wave & 3;          // 2M x 4N waves
  int l15 = lane & 15, g4 = lane >> 4, x7 = l15 & 7;

  f32x4 acc[8][4];
#pragma unroll
  for (int m = 0; m < 8; ++m)
#pragma unroll
    for (int n = 0; n < 4; ++n)
#pragma unroll
      for (int r = 0; r < 4; ++r) acc[m][n][r] = 0.0f;

  // staging: per wave 8KB of each tile; chunk idx = c*512+tid -> row idx>>3,
  // phys slot idx&7; source col pre-swizzled (involution with read side).
  const int scol = (((lane & 7) ^ (lane >> 3)) << 4);
  const size_t sA = ((size_t)(bm * 256 + wave * 8 + (lane >> 3))) * 2048 + scol;
  const size_t sB = ((size_t)(bn * 256 + wave * 8 + (lane >> 3))) * 2048 + scol;
  const int woff = wave * 1024;

#define STG_T(SRC, SOFF, DB, KT)                                              \
  do {                                                                        \
    gload_lds16((SRC) + (SOFF) + (size_t)(KT) * 128, Lds + (DB) + woff);      \
    gload_lds16((SRC) + (SOFF) + 131072 + (size_t)(KT) * 128,                 \
                Lds + (DB) + 8192 + woff);                                    \
    gload_lds16((SRC) + (SOFF) + 262144 + (size_t)(KT) * 128,                 \
                Lds + (DB) + 16384 + woff);                                   \
    gload_lds16((SRC) + (SOFF) + 393216 + (size_t)(KT) * 128,                 \
                Lds + (DB) + 24576 + woff);                                   \
  } while (0)
#define STG_AB(SLOT, KT)                                                      \
  do {                                                                        \
    STG_T(Xb, sA, (SLOT) * 32768, KT);                                        \
    STG_T(Wb, sB, 65536 + (SLOT) * 32768, KT);                                \
  } while (0)

  // fragment pointers (per dbuf-slot offsets added as literals)
  const int aRow = l15 * 128;
  const int sw0 = ((g4) ^ x7) << 4;       // K-half 0 slots 0-3
  const int sw1 = ((4 + g4) ^ x7) << 4;   // K-half 1 slots 4-7
  const char* apk0 = Lds + wr * 16384 + aRow + sw0;
  const char* apk1 = Lds + wr * 16384 + aRow + sw1;
  const char* bpk0 = Lds + 65536 + (wc >> 1) * 16384 + (wc & 1) * 8192 + aRow + sw0;
  const char* bpk1 = Lds + 65536 + (wc >> 1) * 16384 + (wc & 1) * 8192 + aRow + sw1;

  bf16x8 a0, a1, a2, a3, b0, b1, b2, b3;

#define PHASE(APK, BPK, SLO, MH, DO_B, MI0)                                   \
  do {                                                                        \
    if (DO_B) {                                                               \
      b0 = *(const bf16x8*)((APK != APK ? (const char*)0 : (BPK)) + (SLO));   \
      b1 = *(const bf16x8*)((BPK) + (SLO) + 2048);                            \
      b2 = *(const bf16x8*)((BPK) + (SLO) + 4096);                            \
      b3 = *(const bf16x8*)((BPK) + (SLO) + 6144);                            \
    }                                                                         \
    a0 = *(const bf16x8*)((APK) + (SLO) + (MH) * 8192);                       \
    a1 = *(const bf16x8*)((APK) + (SLO) + (MH) * 8192 + 2048);                \
    a2 = *(const bf16x8*)((APK) + (SLO) + (MH) * 8192 + 4096);                \
    a3 = *(const bf16x8*)((APK) + (SLO) + (MH) * 8192 + 6144);                \
    __builtin_amdgcn_sched_barrier(0);                                        \
    __builtin_amdgcn_s_barrier();                                             \
    asm volatile("s_waitcnt lgkmcnt(0)" ::: "memory");                        \
    __builtin_amdgcn_sched_barrier(0);                                        \
    __builtin_amdgcn_s_setprio(1);                                            \
    acc[(MI0)+0][0] = MF(a0, b0, acc[(MI0)+0][0]);                            \
    acc[(MI0)+0][1] = MF(a0, b1, acc[(MI0)+0][1]);                            \
    acc[(MI0)+0][2] = MF(a0, b2, acc[(MI0)+0][2]);                            \
    acc[(MI0)+0][3] = MF(a0, b3, acc[(MI0)+0][3]);                            \
    acc[(MI0)+1][0] = MF(a1, b0, acc[(MI0)+1][0]);                            \
    acc[(MI0)+1][1] = MF(a1, b1, acc[(MI0)+1][1]);                            \
    acc[(MI0)+1][2] = MF(a1, b2, acc[(MI0)+1][2]);                            \
    acc[(MI0)+1][3] = MF(a1, b3, acc[(MI0)+1][3]);                            \
    acc[(MI0)+2][0] = MF(a2, b0, acc[(MI0)+2][0]);                            \
    acc[(MI0)+2][1] = MF(a2, b1, acc[(MI0)+2][1]);                            \
    acc[(MI0)+2][2] = MF(a2, b2, acc[(MI0)+2][2]);                            \
    acc[(MI0)+2][3] = MF(a2, b3, acc[(MI0)+2][3]);                            \
    acc[(MI0)+3][0] = MF(a3, b0, acc[(MI0)+3][0]);                            \
    acc[(MI0)+3][1] = MF(a3, b1, acc[(MI0)+3][1]);                            \
    acc[(MI0)+3][2] = MF(a3, b2, acc[(MI0)+3][2]);                            \
    acc[(MI0)+3][3] = MF(a3, b3, acc[(MI0)+3][3]);                            \
    __builtin_amdgcn_s_setprio(0);                                            \
    __builtin_amdgcn_sched_barrier(0);                                        \
    __builtin_amdgcn_s_barrier();                                             \
    asm volatile("" ::: "memory");                                            \
  } while (0)

// group h: read tile h from slot SL=h&1; stage tile h+1 into NSL=(h+1)&1.
#define GROUP(SL, NSL, KTN, DO_STG, VMSTR)                                    \
  do {                                                                        \
    if (DO_STG) STG_AB(NSL, KTN);                                             \
    asm volatile(VMSTR ::: "memory");                                         \
    __builtin_amdgcn_s_barrier();                                             \
    asm volatile("" ::: "memory");                                            \
    PHASE(apk0, bpk0, (SL) * 32768, 0, 1, 0);                                 \
    PHASE(apk0, bpk0, (SL) * 32768, 1, 0, 4);                                 \
    PHASE(apk1, bpk1, (SL) * 32768, 0, 1, 0);                                 \
    PHASE(apk1, bpk1, (SL) * 32768, 1, 0, 4);                                 \
  } while (0)

  // prologue: stage tile 0 -> slot 0
  STG_AB(0, 0);

#pragma unroll 1
  for (int h = 0; h < 14; h += 2) {
    GROUP(0, 1, h + 1, 1, "s_waitcnt vmcnt(8)");
    GROUP(1, 0, h + 2, 1, "s_waitcnt vmcnt(8)");
  }
  GROUP(0, 1, 15, 1, "s_waitcnt vmcnt(8)");
  GROUP(1, 0, 0, 0, "s_waitcnt vmcnt(0)");

#undef GROUP
#undef PHASE
#undef STG_AB
#undef STG_T

  const float* bias = a.bias[job];
  short* out = a.out[job];
  int tshift = a.tshift[job], tmask = (1 << tshift) - 1, mode = a.mode[job];
  float scl = a.scale[job];
#pragma unroll
  for (int m = 0; m < 8; ++m) {
    int rowb = bm * 256 + wr * 128 + m * 16 + (g4 << 2);
#pragma unroll
    for (int n = 0; n < 4; ++n) {
      int col = bn * 256 + wc * 64 + n * 16 + l15;
      float bv = bias[col];
      int head = col >> 6, d = col & 63;
#pragma unroll
      for (int r = 0; r < 4; ++r) {
        int row = rowb + r;
        int bb = row >> tshift, tk = row & tmask;
        float val = (acc[m][n][r] + bv) * scl;
        size_t idx;
        if (mode == 0)
          idx = ((((size_t)bb * NHEAD + head) << tshift) + tk) * 64 + d;
        else
          idx = ((((size_t)bb * NHEAD + head) * 64 + d) << tshift) + tk;
        out[idx] = f2bf(val);
      }
    }
  }
}

// ---- kernel 4: swapped-QK^T 32x32 flash attention (r13 version) ------------
__global__ __launch_bounds__(128, 2) void attn32(
    const short* __restrict__ qall, const short* __restrict__ kall,
    const short* __restrict__ vTall, const short* __restrict__ kqall,
    const short* __restrict__ kkall, const short* __restrict__ kvTall,
    const float* __restrict__ amask, const float* __restrict__ emask,
    float* __restrict__ out) {
  __shared__ char KT[2][8192];
  __shared__ char VT[2][8192];
  __shared__ float red[2][32];

  int lid = blockIdx.x;
  int id = (lid & 7) * 128 + (lid >> 3);
  int bh = id >> 4, qb = id & 15;
  int b = bh >> 4, h = bh & 15;
  int lane = threadIdx.x & 63, wave = threadIdx.x >> 6;
  int l31 = lane & 31, hi = lane >> 5, x7 = l31 & 7;
  int qrow0 = qb * 64 + wave * 32;

  bf16x8 qcur[4];
  {
    const short* qp = qall + ((size_t)bh * SEQ + qrow0 + l31) * 64;
#pragma unroll
    for (int i = 0; i < 4; ++i)
      qcur[i] = *(const bf16x8*)(qp + i * 16 + hi * 8);
  }

  const char* kb0 = (const char*)(kall + (size_t)bh * SEQ * 64);
  const char* vb0 = (const char*)(vTall + (size_t)bh * 64 * SEQ);
  const char* kb1 = (const char*)(kkall + (size_t)bh * KENC * 64);
  const char* vb1 = (const char*)(kvTall + (size_t)bh * 64 * KENC);
  const float* mpc = amask + (size_t)b * SEQ;

  auto STAGE = [&](int pb, const char* kb, const char* vb, size_t vrowb, int kt) {
    int t0 = threadIdx.x;
#pragma unroll
    for (int c = 0; c < 4; ++c) {
      int idx = c * 128 + t0;
      int row = idx >> 3, phys = idx & 7;
      int lg = phys ^ (row & 7);
      gload_lds16(kb + ((size_t)(kt * 64 + row)) * 128 + lg * 16,
                  KT[pb] + idx * 16);
      gload_lds16(vb + (size_t)row * vrowb + (size_t)kt * 128 + lg * 16,
                  VT[pb] + idx * 16);
    }
  };

  STAGE(0, kb0, vb0, SEQ * 2, 0);

  f32x16 ctx0, ctx1, c10, c11;
#pragma unroll
  for (int r = 0; r < 16; ++r) { ctx0[r] = 0.f; ctx1[r] = 0.f; c10[r] = 0.f; c11[r] = 0.f; }
  float mr = -1e30f, lr = 0.f;

#pragma unroll 1
  for (int t = 0; t < 24; ++t) {
    int p = t & 1;
    __syncthreads();
    if (t < 23) {
      int tn = t + 1;
      if (tn >= 16) STAGE(p ^ 1, kb1, vb1, KENC * 2, tn - 16);
      else          STAGE(p ^ 1, kb0, vb0, SEQ * 2, tn);
    }
    if (t == 16) {
      if (!hi) red[wave][l31] = lr;
      asm volatile("s_waitcnt lgkmcnt(0)" ::: "memory");
#pragma unroll
      for (int r2 = 0; r2 < 4; ++r2) {
        f4v lv = *(const f4v*)(&red[wave][r2 * 8 + 4 * hi]);
#pragma unroll
        for (int j2 = 0; j2 < 4; ++j2) {
          float li = __builtin_amdgcn_rcpf(lv[j2]);
          int r = r2 * 4 + j2;
          c10[r] = ctx0[r] * li;  ctx0[r] = 0.f;
          c11[r] = ctx1[r] * li;  ctx1[r] = 0.f;
        }
      }
      mr = -1e30f; lr = 0.f;
      const short* kqp = kqall + ((size_t)bh * SEQ + qrow0 + l31) * 64;
#pragma unroll
      for (int i = 0; i < 4; ++i)
        qcur[i] = *(const bf16x8*)(kqp + i * 16 + hi * 8);
      mpc = emask + (size_t)b * KENC;
    }
    int kt = (t >= 16) ? t - 16 : t;
    const char* Kp = KT[p];
    const char* Vp = VT[p];

    f32x16 s0, s1;
#pragma unroll
    for (int r = 0; r < 16; ++r) { s0[r] = 0.f; s1[r] = 0.f; }
    __builtin_amdgcn_s_setprio(1);
#pragma unroll
    for (int i = 0; i < 4; ++i) {
      bf16x8 kf = *(const bf16x8*)(Kp + (l31)*128 + (((2 * i + hi) ^ x7) << 4));
      s0 = __builtin_amdgcn_mfma_f32_32x32x16_bf16(kf, qcur[i], s0, 0, 0, 0);
    }
#pragma unroll
    for (int i = 0; i < 4; ++i) {
      bf16x8 kf = *(const bf16x8*)(Kp + (32 + l31) * 128 + (((2 * i + hi) ^ x7) << 4));
      s1 = __builtin_amdgcn_mfma_f32_32x32x16_bf16(kf, qcur[i], s1, 0, 0, 0);
    }
    __builtin_amdgcn_s_setprio(0);

    const float* mp = mpc + kt * 64;
#pragma unroll
    for (int r2 = 0; r2 < 4; ++r2) {
      f4v ma = *(const f4v*)(mp + r2 * 8 + 4 * hi);
      f4v mb = *(const f4v*)(mp + 32 + r2 * 8 + 4 * hi);
#pragma unroll
      for (int j2 = 0; j2 < 4; ++j2) {
        s0[r2 * 4 + j2] = fmaf(ma[j2], LOG2E, s0[r2 * 4 + j2]);
        s1[r2 * 4 + j2] = fmaf(mb[j2], LOG2E, s1[r2 * 4 + j2]);
      }
    }

    float mx = fmaxf(tmax16(s0), tmax16(s1));
    mx = fmaxf(mx, __int_as_float(__shfl_xor(__float_as_int(mx), 32)));

    if (!__all(mx <= mr + 12.f)) {
      float mn = fmaxf(mr, mx);
      float scl = __builtin_amdgcn_exp2f(mr - mn);
      mr = mn; lr *= scl;
      if (!hi) red[wave][l31] = scl;
      asm volatile("s_waitcnt lgkmcnt(0)" ::: "memory");
#pragma unroll
      for (int r2 = 0; r2 < 4; ++r2) {
        f4v sv = *(const f4v*)(&red[wave][r2 * 8 + 4 * hi]);
#pragma unroll
        for (int j2 = 0; j2 < 4; ++j2) {
          ctx0[r2 * 4 + j2] *= sv[j2];
          ctx1[r2 * 4 + j2] *= sv[j2];
        }
      }
    }

#pragma unroll
    for (int r = 0; r < 16; ++r) s0[r] = __builtin_amdgcn_exp2f(s0[r] - mr);
#pragma unroll
    for (int r = 0; r < 16; ++r) s1[r] = __builtin_amdgcn_exp2f(s1[r] - mr);
    float rs = tsum16(s0) + tsum16(s1);
    rs += __int_as_float(__shfl_xor(__float_as_int(rs), 32));
    lr += rs;

#pragma unroll
    for (int s = 0; s < 2; ++s) {
      const f32x16& sv = s ? s1 : s0;
      unsigned W[8];
#pragma unroll
      for (int r2 = 0; r2 < 4; ++r2) {
        asm("v_cvt_pk_bf16_f32 %0, %1, %2"
            : "=v"(W[r2 * 2]) : "v"(sv[r2 * 4 + 0]), "v"(sv[r2 * 4 + 1]));
        asm("v_cvt_pk_bf16_f32 %0, %1, %2"
            : "=v"(W[r2 * 2 + 1]) : "v"(sv[r2 * 4 + 2]), "v"(sv[r2 * 4 + 3]));
      }
#pragma unroll
      for (int jr = 0; jr < 2; ++jr) {
        unsigned sendA = hi ? W[(2 * jr) * 2]     : W[(2 * jr + 1) * 2];
        unsigned sendB = hi ? W[(2 * jr) * 2 + 1] : W[(2 * jr + 1) * 2 + 1];
        unsigned rA = (unsigned)__shfl_xor((int)sendA, 32);
        unsigned rB = (unsigned)__shfl_xor((int)sendB, 32);
        union { unsigned u[4]; bf16x8 v; } pa;
        if (!hi) { pa.u[0] = W[2 * jr * 2]; pa.u[1] = W[2 * jr * 2 + 1];
                   pa.u[2] = rA;            pa.u[3] = rB; }
        else     { pa.u[0] = rA;            pa.u[1] = rB;
                   pa.u[2] = W[(2 * jr + 1) * 2]; pa.u[3] = W[(2 * jr + 1) * 2 + 1]; }
        int j = s * 2 + jr;
        __builtin_amdgcn_s_setprio(1);
        bf16x8 vf0 = *(const bf16x8*)(Vp + (l31)*128 + (((2 * j + hi) ^ x7) << 4));
        ctx0 = __builtin_amdgcn_mfma_f32_32x32x16_bf16(pa.v, vf0, ctx0, 0, 0, 0);
        bf16x8 vf1 = *(const bf16x8*)(Vp + (32 + l31) * 128 + (((2 * j + hi) ^ x7) << 4));
        ctx1 = __builtin_amdgcn_mfma_f32_32x32x16_bf16(pa.v, vf1, ctx1, 0, 0, 0);
        __builtin_amdgcn_s_setprio(0);
      }
    }
  }

  if (!hi) red[wave][l31] = lr;
  asm volatile("s_waitcnt lgkmcnt(0)" ::: "memory");
  float* op = out + ((size_t)b * SEQ) * HDIM + h * 64 + l31;
#pragma unroll
  for (int r2 = 0; r2 < 4; ++r2) {
    f4v lv = *(const f4v*)(&red[wave][r2 * 8 + 4 * hi]);
#pragma unroll
    for (int j2 = 0; j2 < 4; ++j2) {
      float li = __builtin_amdgcn_rcpf(lv[j2]);
      int s = qrow0 + r2 * 8 + 4 * hi + j2;
      int r = r2 * 4 + j2;
      op[(size_t)s * HDIM]      = 0.5f * (c10[r] + ctx0[r] * li);
      op[(size_t)s * HDIM + 32] = 0.5f * (c11[r] + ctx1[r] * li);
    }
  }
}

// ---- host launcher ---------------------------------------------------------
extern "C" void kernel_launch(void* const* d_in, const int* in_sizes, int n_in,
                              void* d_out, int out_size, void* d_ws, size_t ws_size,
                              hipStream_t stream) {
  const float* hid = (const float*)d_in[0];
  const float* enc = (const float*)d_in[1];
  const float* amask = (const float*)d_in[2];
  const float* emask = (const float*)d_in[3];

  char* ws = (char*)d_ws;
  short* hbf = (short*)(ws);                        // 8 MB  [B*S,H] bf16
  short* ebf = (short*)(ws + (8u << 20));           // 4 MB  [B*K,H]
  short* wt = (short*)(ws + (12u << 20));           // 12 MB 6x [n][k]
  short* qo = (short*)(ws + (24u << 20));           // 8 MB  [B,NH,S,HD]
  short* ko = (short*)(ws + (32u << 20));           // 8 MB
  short* vT = (short*)(ws + (40u << 20));           // 8 MB  [B,NH,HD,S]
  short* kqo = (short*)(ws + (48u << 20));          // 8 MB
  short* kko = (short*)(ws + (56u << 20));          // 4 MB  [B,NH,K,HD]
  short* kvT = (short*)(ws + (60u << 20));          // 4 MB  [B,NH,HD,K]

  PrepArgs wa;
  for (int j = 0; j < 6; ++j) wa.W[j] = (const float*)d_in[4 + 2 * j];
  prep<<<12288, 256, 0, stream>>>(wa, wt, hid, hbf, (BATCH * SEQ * HDIM) / 4,
                                  enc, ebf, (BATCH * KENC * HDIM) / 4);

  ProjArgs pa;
  const short* Xs[6] = {hbf, hbf, hbf, hbf, ebf, ebf};
  short* outs[6] = {qo, ko, vT, kqo, kko, kvT};
  const int tsh[6] = {10, 10, 10, 10, 9, 9};
  const int md[6] = {0, 0, 1, 0, 0, 1};
  const float qscale = 0.125f * LOG2E;
  const float scl[6] = {qscale, 1.f, 1.f, qscale, 1.f, 1.f};
  for (int j = 0; j < 6; ++j) {
    pa.X[j] = Xs[j];
    pa.Wt[j] = wt + (size_t)j * (HDIM * HDIM);
    pa.bias[j] = (const float*)d_in[5 + 2 * j];
    pa.out[j] = outs[j];
    pa.tshift[j] = tsh[j];
    pa.mode[j] = md[j];
    pa.scale[j] = scl[j];
  }
  proj_gemm8<<<320, 512, 0, stream>>>(pa);

  attn32<<<1024, 128, 0, stream>>>(qo, ko, vT, kqo, kko, kvT, amask, emask,
                                   (float*)d_out);
}

// Round 15
// 142.685 us; speedup vs baseline: 1.1414x; 1.1414x over previous
//
#include <hip/hip_runtime.h>

// ---- constants -------------------------------------------------------------
#define BATCH 4
#define SEQ   1024
#define KENC  512
#define HDIM  1024
#define NHEAD 16
#define HD    64
#define LOG2E 1.44269504088896340736f

typedef __attribute__((ext_vector_type(8))) short bf16x8;
typedef __attribute__((ext_vector_type(4))) float f32x4;
typedef __attribute__((ext_vector_type(16))) float f32x16;
typedef __attribute__((ext_vector_type(4))) float f4v;
typedef __attribute__((ext_vector_type(4))) short s4v;

__device__ __forceinline__ short f2bf(float f) {
  unsigned u = __float_as_uint(f);
  u += 0x7fffu + ((u >> 16) & 1u);   // RNE
  return (short)(u >> 16);
}

__device__ __forceinline__ void gload_lds16(const void* g, void* l) {
  __builtin_amdgcn_global_load_lds(
      (const __attribute__((address_space(1))) void*)g,
      (__attribute__((address_space(3))) void*)l, 16, 0, 0);
}

__device__ __forceinline__ float tmax16(const f32x16& v) {
  float a0 = fmaxf(v[0], v[1]),   a1 = fmaxf(v[2], v[3]);
  float a2 = fmaxf(v[4], v[5]),   a3 = fmaxf(v[6], v[7]);
  float a4 = fmaxf(v[8], v[9]),   a5 = fmaxf(v[10], v[11]);
  float a6 = fmaxf(v[12], v[13]), a7 = fmaxf(v[14], v[15]);
  float b0 = fmaxf(a0, a1), b1 = fmaxf(a2, a3);
  float b2 = fmaxf(a4, a5), b3 = fmaxf(a6, a7);
  return fmaxf(fmaxf(b0, b1), fmaxf(b2, b3));
}
__device__ __forceinline__ float tsum16(const f32x16& v) {
  float a0 = v[0] + v[1],   a1 = v[2] + v[3];
  float a2 = v[4] + v[5],   a3 = v[6] + v[7];
  float a4 = v[8] + v[9],   a5 = v[10] + v[11];
  float a6 = v[12] + v[13], a7 = v[14] + v[15];
  float b0 = a0 + a1, b1 = a2 + a3, b2 = a4 + a5, b3 = a6 + a7;
  return (b0 + b1) + (b2 + b3);
}

#define MF(A, B, C) __builtin_amdgcn_mfma_f32_16x16x32_bf16((A), (B), (C), 0, 0, 0)

// ---- kernel 1: fused prep — weight cast+transpose AND activation casts -----
struct PrepArgs { const float* W[6]; };

__global__ __launch_bounds__(256) void prep(PrepArgs a, short* __restrict__ wt,
                                            const float* __restrict__ hid,
                                            short* __restrict__ hbf, int n4h,
                                            const float* __restrict__ enc,
                                            short* __restrict__ ebf, int n4e) {
  __shared__ float t[32][33];
  int blk = blockIdx.x;
  if (blk < 6144) {
    int j = blk >> 10;
    int r = blk & 1023;
    int cb = (r & 31) * 32, rb = (r >> 5) * 32;
    const float* W = a.W[j];
    short* dst = wt + (size_t)j * (HDIM * HDIM);
    int tx = threadIdx.x & 31, ty = threadIdx.x >> 5;
#pragma unroll
    for (int rr = 0; rr < 4; ++rr)
      t[ty + rr * 8][tx] = W[(size_t)(rb + ty + rr * 8) * HDIM + cb + tx];
    __syncthreads();
#pragma unroll
    for (int rr = 0; rr < 4; ++rr)
      dst[(size_t)(cb + ty + rr * 8) * HDIM + rb + tx] = f2bf(t[tx][ty + rr * 8]);
  } else {
    int i = (blk - 6144) * 256 + threadIdx.x;
    const float* s;
    short* d;
    int j;
    if (i < n4h) { s = hid; d = hbf; j = i; }
    else { j = i - n4h; if (j >= n4e) return; s = enc; d = ebf; }
    f4v v = ((const f4v*)s)[j];
    s4v o;
#pragma unroll
    for (int k = 0; k < 4; ++k) o[k] = f2bf(v[k]);
    ((s4v*)d)[j] = o;
  }
}

// ---- kernel 3: projection GEMM — 128x128 tile, BK=64, double-buffer --------
// Hypothesis test: 16 K-steps (vs 32) at identical LDS/occupancy halves the
// per-step fixed cost (barrier convoy). Stage tile t+1 during t; drain at
// step end (1 step ≈ 1200cyc slack covers L2/HBM). Literal offsets, x2 unroll.
struct ProjArgs {
  const short* X[6];
  const short* Wt[6];
  const float* bias[6];
  short* out[6];
  int M[6];
  int tshift[6];
  int mode[6];
  float scale[6];
};

__global__ __launch_bounds__(256) void proj_gemm(ProjArgs a) {
  int job = blockIdx.z;
  int M = a.M[job];
  int by = blockIdx.y;
  if (by * 128 >= M) return;
  int bx = blockIdx.x;
  const short* X = a.X[job];
  const short* W = a.Wt[job];

  __shared__ __align__(16) char Lds[65536];  // buf0: A@0 B@16K; buf1: A@32K B@48K

  int tid = threadIdx.x, lane = tid & 63, wave = tid >> 6;
  int wr = wave >> 1, wc = wave & 1;
  int l15 = lane & 15, g4 = lane >> 4, x7 = l15 & 7;

  f32x4 acc[4][4];
#pragma unroll
  for (int m = 0; m < 4; ++m)
#pragma unroll
    for (int n = 0; n < 4; ++n)
#pragma unroll
      for (int r = 0; r < 4; ++r) acc[m][n][r] = 0.0f;

  int arow = by * 128, brow = bx * 128;

  // staging: wave stages rows wave*32 .. +31 (4 chunks of 8 rows); lane ->
  // row chunk*8 + (lane>>3), phys 16B-slot lane&7; source slot pre-swizzled
  // with (row&7) = lane>>3 (involution with read side).
  const int srow = lane >> 3;
  const int scol = (((lane & 7) ^ srow) << 4);
  const char* Xb = (const char*)X;
  const char* Wb = (const char*)W;
  const size_t sA = ((size_t)(arow + wave * 32 + srow)) * 2048 + scol;
  const size_t sB = ((size_t)(brow + wave * 32 + srow)) * 2048 + scol;
  const int woff = wave * 4096;

#define STG_A(BUF, KT)                                                        \
  do {                                                                        \
    gload_lds16(Xb + sA + (size_t)(KT) * 128,          Lds + (BUF) + woff);   \
    gload_lds16(Xb + sA + (size_t)(KT) * 128 + 16384,  Lds + (BUF) + woff + 1024); \
    gload_lds16(Xb + sA + (size_t)(KT) * 128 + 32768,  Lds + (BUF) + woff + 2048); \
    gload_lds16(Xb + sA + (size_t)(KT) * 128 + 49152,  Lds + (BUF) + woff + 3072); \
  } while (0)
#define STG_B(BUF, KT)                                                        \
  do {                                                                        \
    gload_lds16(Wb + sB + (size_t)(KT) * 128,          Lds + (BUF) + 16384 + woff); \
    gload_lds16(Wb + sB + (size_t)(KT) * 128 + 16384,  Lds + (BUF) + 16384 + woff + 1024); \
    gload_lds16(Wb + sB + (size_t)(KT) * 128 + 32768,  Lds + (BUF) + 16384 + woff + 2048); \
    gload_lds16(Wb + sB + (size_t)(KT) * 128 + 49152,  Lds + (BUF) + 16384 + woff + 3072); \
  } while (0)

  // fragment addressing: row has 8 16B-slots; K-half kh uses slot kh*4+g4,
  // swizzled by XOR x7. (4|g4)^x7 = 4 ^ (g4^x7) -> kh=1 offset = kh0 ^ 0x40.
  const int sw0 = (g4 ^ x7) << 4;
  const int aoff = (wr * 64 + l15) * 128 + sw0;            // + m*2048, kh^0x40
  const int boff = 16384 + (wc * 64 + l15) * 128 + sw0;

  // prologue: stage tile 0 -> buf0
  STG_A(0, 0);
  STG_B(0, 0);
  asm volatile("s_waitcnt vmcnt(0)" ::: "memory");
  __builtin_amdgcn_s_barrier();
  asm volatile("" ::: "memory");

#define HALF(BO, KH, A0, A1, A2, A3, B0, B1, B2, B3)                          \
  do {                                                                        \
    A0 = *(const bf16x8*)(Lds + (BO) + 0 * 2048 + (aoff ^ ((KH) * 0x40)));    \
    A1 = *(const bf16x8*)(Lds + (BO) + 1 * 2048 + (aoff ^ ((KH) * 0x40)));    \
    A2 = *(const bf16x8*)(Lds + (BO) + 2 * 2048 + (aoff ^ ((KH) * 0x40)));    \
    A3 = *(const bf16x8*)(Lds + (BO) + 3 * 2048 + (aoff ^ ((KH) * 0x40)));    \
    B0 = *(const bf16x8*)(Lds + (BO) + 0 * 2048 + (boff ^ ((KH) * 0x40)));    \
    B1 = *(const bf16x8*)(Lds + (BO) + 1 * 2048 + (boff ^ ((KH) * 0x40)));    \
    B2 = *(const bf16x8*)(Lds + (BO) + 2 * 2048 + (boff ^ ((KH) * 0x40)));    \
    B3 = *(const bf16x8*)(Lds + (BO) + 3 * 2048 + (boff ^ ((KH) * 0x40)));    \
  } while (0)

#define MM16(A0, A1, A2, A3, B0, B1, B2, B3)                                  \
  do {                                                                        \
    __builtin_amdgcn_s_setprio(1);                                            \
    acc[0][0] = MF(A0, B0, acc[0][0]);                                        \
    acc[0][1] = MF(A0, B1, acc[0][1]);                                        \
    acc[0][2] = MF(A0, B2, acc[0][2]);                                        \
    acc[0][3] = MF(A0, B3, acc[0][3]);                                        \
    acc[1][0] = MF(A1, B0, acc[1][0]);                                        \
    acc[1][1] = MF(A1, B1, acc[1][1]);                                        \
    acc[1][2] = MF(A1, B2, acc[1][2]);                                        \
    acc[1][3] = MF(A1, B3, acc[1][3]);                                        \
    acc[2][0] = MF(A2, B0, acc[2][0]);                                        \
    acc[2][1] = MF(A2, B1, acc[2][1]);                                        \
    acc[2][2] = MF(A2, B2, acc[2][2]);                                        \
    acc[2][3] = MF(A2, B3, acc[2][3]);                                        \
    acc[3][0] = MF(A3, B0, acc[3][0]);                                        \
    acc[3][1] = MF(A3, B1, acc[3][1]);                                        \
    acc[3][2] = MF(A3, B2, acc[3][2]);                                        \
    acc[3][3] = MF(A3, B3, acc[3][3]);                                        \
    __builtin_amdgcn_s_setprio(0);                                            \
  } while (0)

// one BK=64 step: 16 frag reads + 8 staging gloads interleaved + 32 MFMA,
// single vmcnt+barrier at end.
#define STEP(BO, OB, KTN, DO_STG, VMW, DO_BAR)                                \
  do {                                                                        \
    bf16x8 pa0, pa1, pa2, pa3, pb0, pb1, pb2, pb3;                            \
    bf16x8 qa0, qa1, qa2, qa3, qb0, qb1, qb2, qb3;                            \
    HALF(BO, 0, pa0, pa1, pa2, pa3, pb0, pb1, pb2, pb3);                      \
    if (DO_STG) STG_A(OB, KTN);                                               \
    MM16(pa0, pa1, pa2, pa3, pb0, pb1, pb2, pb3);                             \
    HALF(BO, 1, qa0, qa1, qa2, qa3, qb0, qb1, qb2, qb3);                      \
    if (DO_STG) STG_B(OB, KTN);                                               \
    MM16(qa0, qa1, qa2, qa3, qb0, qb1, qb2, qb3);                             \
    asm volatile(VMW ::: "memory");                                           \
    if (DO_BAR) {                                                             \
      __builtin_amdgcn_s_barrier();                                           \
      asm volatile("" ::: "memory");                                          \
    }                                                                         \
  } while (0)

#pragma unroll 1
  for (int it = 0; it < 7; ++it) {
    int t0 = it * 2;
    STEP(0,     32768, t0 + 1, 1, "s_waitcnt vmcnt(0)", 1);
    STEP(32768, 0,     t0 + 2, 1, "s_waitcnt vmcnt(0)", 1);
  }
  STEP(0,     32768, 15, 1, "s_waitcnt vmcnt(0)", 1);
  STEP(32768, 0,     0,  0, "s_nop 0", 0);

#undef STEP
#undef MM16
#undef HALF
#undef STG_A
#undef STG_B

  const float* bias = a.bias[job];
  short* out = a.out[job];
  int tshift = a.tshift[job], tmask = (1 << tshift) - 1, mode = a.mode[job];
  float scl = a.scale[job];
#pragma unroll
  for (int m = 0; m < 4; ++m) {
    int rowb = arow + wr * 64 + m * 16 + (g4 << 2);
#pragma unroll
    for (int n = 0; n < 4; ++n) {
      int col = brow + wc * 64 + n * 16 + l15;
      float bv = bias[col];
      int head = col >> 6, d = col & 63;
#pragma unroll
      for (int r = 0; r < 4; ++r) {
        int row = rowb + r;
        int bb = row >> tshift, tk = row & tmask;
        float val = (acc[m][n][r] + bv) * scl;
        size_t idx;
        if (mode == 0)
          idx = ((((size_t)bb * NHEAD + head) << tshift) + tk) * 64 + d;
        else
          idx = ((((size_t)bb * NHEAD + head) * 64 + d) << tshift) + tk;
        out[idx] = f2bf(val);
      }
    }
  }
}

// ---- kernel 4: swapped-QK^T 32x32 flash attention (r13 version) ------------
__global__ __launch_bounds__(128, 2) void attn32(
    const short* __restrict__ qall, const short* __restrict__ kall,
    const short* __restrict__ vTall, const short* __restrict__ kqall,
    const short* __restrict__ kkall, const short* __restrict__ kvTall,
    const float* __restrict__ amask, const float* __restrict__ emask,
    float* __restrict__ out) {
  __shared__ char KT[2][8192];
  __shared__ char VT[2][8192];
  __shared__ float red[2][32];

  int lid = blockIdx.x;
  int id = (lid & 7) * 128 + (lid >> 3);
  int bh = id >> 4, qb = id & 15;
  int b = bh >> 4, h = bh & 15;
  int lane = threadIdx.x & 63, wave = threadIdx.x >> 6;
  int l31 = lane & 31, hi = lane >> 5, x7 = l31 & 7;
  int qrow0 = qb * 64 + wave * 32;

  bf16x8 qcur[4];
  {
    const short* qp = qall + ((size_t)bh * SEQ + qrow0 + l31) * 64;
#pragma unroll
    for (int i = 0; i < 4; ++i)
      qcur[i] = *(const bf16x8*)(qp + i * 16 + hi * 8);
  }

  const char* kb0 = (const char*)(kall + (size_t)bh * SEQ * 64);
  const char* vb0 = (const char*)(vTall + (size_t)bh * 64 * SEQ);
  const char* kb1 = (const char*)(kkall + (size_t)bh * KENC * 64);
  const char* vb1 = (const char*)(kvTall + (size_t)bh * 64 * KENC);
  const float* mpc = amask + (size_t)b * SEQ;

  auto STAGE = [&](int pb, const char* kb, const char* vb, size_t vrowb, int kt) {
    int t0 = threadIdx.x;
#pragma unroll
    for (int c = 0; c < 4; ++c) {
      int idx = c * 128 + t0;
      int row = idx >> 3, phys = idx & 7;
      int lg = phys ^ (row & 7);
      gload_lds16(kb + ((size_t)(kt * 64 + row)) * 128 + lg * 16,
                  KT[pb] + idx * 16);
      gload_lds16(vb + (size_t)row * vrowb + (size_t)kt * 128 + lg * 16,
                  VT[pb] + idx * 16);
    }
  };

  STAGE(0, kb0, vb0, SEQ * 2, 0);

  f32x16 ctx0, ctx1, c10, c11;
#pragma unroll
  for (int r = 0; r < 16; ++r) { ctx0[r] = 0.f; ctx1[r] = 0.f; c10[r] = 0.f; c11[r] = 0.f; }
  float mr = -1e30f, lr = 0.f;

#pragma unroll 1
  for (int t = 0; t < 24; ++t) {
    int p = t & 1;
    __syncthreads();
    if (t < 23) {
      int tn = t + 1;
      if (tn >= 16) STAGE(p ^ 1, kb1, vb1, KENC * 2, tn - 16);
      else          STAGE(p ^ 1, kb0, vb0, SEQ * 2, tn);
    }
    if (t == 16) {
      if (!hi) red[wave][l31] = lr;
      asm volatile("s_waitcnt lgkmcnt(0)" ::: "memory");
#pragma unroll
      for (int r2 = 0; r2 < 4; ++r2) {
        f4v lv = *(const f4v*)(&red[wave][r2 * 8 + 4 * hi]);
#pragma unroll
        for (int j2 = 0; j2 < 4; ++j2) {
          float li = __builtin_amdgcn_rcpf(lv[j2]);
          int r = r2 * 4 + j2;
          c10[r] = ctx0[r] * li;  ctx0[r] = 0.f;
          c11[r] = ctx1[r] * li;  ctx1[r] = 0.f;
        }
      }
      mr = -1e30f; lr = 0.f;
      const short* kqp = kqall + ((size_t)bh * SEQ + qrow0 + l31) * 64;
#pragma unroll
      for (int i = 0; i < 4; ++i)
        qcur[i] = *(const bf16x8*)(kqp + i * 16 + hi * 8);
      mpc = emask + (size_t)b * KENC;
    }
    int kt = (t >= 16) ? t - 16 : t;
    const char* Kp = KT[p];
    const char* Vp = VT[p];

    f32x16 s0, s1;
#pragma unroll
    for (int r = 0; r < 16; ++r) { s0[r] = 0.f; s1[r] = 0.f; }
    __builtin_amdgcn_s_setprio(1);
#pragma unroll
    for (int i = 0; i < 4; ++i) {
      bf16x8 kf = *(const bf16x8*)(Kp + (l31)*128 + (((2 * i + hi) ^ x7) << 4));
      s0 = __builtin_amdgcn_mfma_f32_32x32x16_bf16(kf, qcur[i], s0, 0, 0, 0);
    }
#pragma unroll
    for (int i = 0; i < 4; ++i) {
      bf16x8 kf = *(const bf16x8*)(Kp + (32 + l31) * 128 + (((2 * i + hi) ^ x7) << 4));
      s1 = __builtin_amdgcn_mfma_f32_32x32x16_bf16(kf, qcur[i], s1, 0, 0, 0);
    }
    __builtin_amdgcn_s_setprio(0);

    const float* mp = mpc + kt * 64;
#pragma unroll
    for (int r2 = 0; r2 < 4; ++r2) {
      f4v ma = *(const f4v*)(mp + r2 * 8 + 4 * hi);
      f4v mb = *(const f4v*)(mp + 32 + r2 * 8 + 4 * hi);
#pragma unroll
      for (int j2 = 0; j2 < 4; ++j2) {
        s0[r2 * 4 + j2] = fmaf(ma[j2], LOG2E, s0[r2 * 4 + j2]);
        s1[r2 * 4 + j2] = fmaf(mb[j2], LOG2E, s1[r2 * 4 + j2]);
      }
    }

    float mx = fmaxf(tmax16(s0), tmax16(s1));
    mx = fmaxf(mx, __int_as_float(__shfl_xor(__float_as_int(mx), 32)));

    if (!__all(mx <= mr + 12.f)) {
      float mn = fmaxf(mr, mx);
      float scl = __builtin_amdgcn_exp2f(mr - mn);
      mr = mn; lr *= scl;
      if (!hi) red[wave][l31] = scl;
      asm volatile("s_waitcnt lgkmcnt(0)" ::: "memory");
#pragma unroll
      for (int r2 = 0; r2 < 4; ++r2) {
        f4v sv = *(const f4v*)(&red[wave][r2 * 8 + 4 * hi]);
#pragma unroll
        for (int j2 = 0; j2 < 4; ++j2) {
          ctx0[r2 * 4 + j2] *= sv[j2];
          ctx1[r2 * 4 + j2] *= sv[j2];
        }
      }
    }

#pragma unroll
    for (int r = 0; r < 16; ++r) s0[r] = __builtin_amdgcn_exp2f(s0[r] - mr);
#pragma unroll
    for (int r = 0; r < 16; ++r) s1[r] = __builtin_amdgcn_exp2f(s1[r] - mr);
    float rs = tsum16(s0) + tsum16(s1);
    rs += __int_as_float(__shfl_xor(__float_as_int(rs), 32));
    lr += rs;

#pragma unroll
    for (int s = 0; s < 2; ++s) {
      const f32x16& sv = s ? s1 : s0;
      unsigned W[8];
#pragma unroll
      for (int r2 = 0; r2 < 4; ++r2) {
        asm("v_cvt_pk_bf16_f32 %0, %1, %2"
            : "=v"(W[r2 * 2]) : "v"(sv[r2 * 4 + 0]), "v"(sv[r2 * 4 + 1]));
        asm("v_cvt_pk_bf16_f32 %0, %1, %2"
            : "=v"(W[r2 * 2 + 1]) : "v"(sv[r2 * 4 + 2]), "v"(sv[r2 * 4 + 3]));
      }
#pragma unroll
      for (int jr = 0; jr < 2; ++jr) {
        unsigned sendA = hi ? W[(2 * jr) * 2]     : W[(2 * jr + 1) * 2];
        unsigned sendB = hi ? W[(2 * jr) * 2 + 1] : W[(2 * jr + 1) * 2 + 1];
        unsigned rA = (unsigned)__shfl_xor((int)sendA, 32);
        unsigned rB = (unsigned)__shfl_xor((int)sendB, 32);
        union { unsigned u[4]; bf16x8 v; } pa;
        if (!hi) { pa.u[0] = W[2 * jr * 2]; pa.u[1] = W[2 * jr * 2 + 1];
                   pa.u[2] = rA;            pa.u[3] = rB; }
        else     { pa.u[0] = rA;            pa.u[1] = rB;
                   pa.u[2] = W[(2 * jr + 1) * 2]; pa.u[3] = W[(2 * jr + 1) * 2 + 1]; }
        int j = s * 2 + jr;
        __builtin_amdgcn_s_setprio(1);
        bf16x8 vf0 = *(const bf16x8*)(Vp + (l31)*128 + (((2 * j + hi) ^ x7) << 4));
        ctx0 = __builtin_amdgcn_mfma_f32_32x32x16_bf16(pa.v, vf0, ctx0, 0, 0, 0);
        bf16x8 vf1 = *(const bf16x8*)(Vp + (32 + l31) * 128 + (((2 * j + hi) ^ x7) << 4));
        ctx1 = __builtin_amdgcn_mfma_f32_32x32x16_bf16(pa.v, vf1, ctx1, 0, 0, 0);
        __builtin_amdgcn_s_setprio(0);
      }
    }
  }

  if (!hi) red[wave][l31] = lr;
  asm volatile("s_waitcnt lgkmcnt(0)" ::: "memory");
  float* op = out + ((size_t)b * SEQ) * HDIM + h * 64 + l31;
#pragma unroll
  for (int r2 = 0; r2 < 4; ++r2) {
    f4v lv = *(const f4v*)(&red[wave][r2 * 8 + 4 * hi]);
#pragma unroll
    for (int j2 = 0; j2 < 4; ++j2) {
      float li = __builtin_amdgcn_rcpf(lv[j2]);
      int s = qrow0 + r2 * 8 + 4 * hi + j2;
      int r = r2 * 4 + j2;
      op[(size_t)s * HDIM]      = 0.5f * (c10[r] + ctx0[r] * li);
      op[(size_t)s * HDIM + 32] = 0.5f * (c11[r] + ctx1[r] * li);
    }
  }
}

// ---- host launcher ---------------------------------------------------------
extern "C" void kernel_launch(void* const* d_in, const int* in_sizes, int n_in,
                              void* d_out, int out_size, void* d_ws, size_t ws_size,
                              hipStream_t stream) {
  const float* hid = (const float*)d_in[0];
  const float* enc = (const float*)d_in[1];
  const float* amask = (const float*)d_in[2];
  const float* emask = (const float*)d_in[3];

  char* ws = (char*)d_ws;
  short* hbf = (short*)(ws);                        // 8 MB  [B*S,H] bf16
  short* ebf = (short*)(ws + (8u << 20));           // 4 MB  [B*K,H]
  short* wt = (short*)(ws + (12u << 20));           // 12 MB 6x [n][k]
  short* qo = (short*)(ws + (24u << 20));           // 8 MB  [B,NH,S,HD]
  short* ko = (short*)(ws + (32u << 20));           // 8 MB
  short* vT = (short*)(ws + (40u << 20));           // 8 MB  [B,NH,HD,S]
  short* kqo = (short*)(ws + (48u << 20));          // 8 MB
  short* kko = (short*)(ws + (56u << 20));          // 4 MB  [B,NH,K,HD]
  short* kvT = (short*)(ws + (60u << 20));          // 4 MB  [B,NH,HD,K]

  PrepArgs wa;
  for (int j = 0; j < 6; ++j) wa.W[j] = (const float*)d_in[4 + 2 * j];
  prep<<<12288, 256, 0, stream>>>(wa, wt, hid, hbf, (BATCH * SEQ * HDIM) / 4,
                                  enc, ebf, (BATCH * KENC * HDIM) / 4);

  ProjArgs pa;
  const short* Xs[6] = {hbf, hbf, hbf, hbf, ebf, ebf};
  short* outs[6] = {qo, ko, vT, kqo, kko, kvT};
  const int Ms[6] = {4096, 4096, 4096, 4096, 2048, 2048};
  const int tsh[6] = {10, 10, 10, 10, 9, 9};
  const int md[6] = {0, 0, 1, 0, 0, 1};
  const float qscale = 0.125f * LOG2E;
  const float scl[6] = {qscale, 1.f, 1.f, qscale, 1.f, 1.f};
  for (int j = 0; j < 6; ++j) {
    pa.X[j] = Xs[j];
    pa.Wt[j] = wt + (size_t)j * (HDIM * HDIM);
    pa.bias[j] = (const float*)d_in[5 + 2 * j];
    pa.out[j] = outs[j];
    pa.M[j] = Ms[j];
    pa.tshift[j] = tsh[j];
    pa.mode[j] = md[j];
    pa.scale[j] = scl[j];
  }
  proj_gemm<<<dim3(8, 32, 6), 256, 0, stream>>>(pa);

  attn32<<<1024, 128, 0, stream>>>(qo, ko, vT, kqo, kko, kvT, amask, emask,
                                   (float*)d_out);
}

// Round 16
// 140.000 us; speedup vs baseline: 1.1633x; 1.0192x over previous
//
#include <hip/hip_runtime.h>

// ---- constants -------------------------------------------------------------
#define BATCH 4
#define SEQ   1024
#define KENC  512
#define HDIM  1024
#define NHEAD 16
#define HD    64
#define LOG2E 1.44269504088896340736f

typedef __attribute__((ext_vector_type(8))) short bf16x8;
typedef __attribute__((ext_vector_type(4))) float f32x4;
typedef __attribute__((ext_vector_type(16))) float f32x16;
typedef __attribute__((ext_vector_type(4))) float f4v;
typedef __attribute__((ext_vector_type(4))) short s4v;

__device__ __forceinline__ short f2bf(float f) {
  unsigned u = __float_as_uint(f);
  u += 0x7fffu + ((u >> 16) & 1u);   // RNE
  return (short)(u >> 16);
}

__device__ __forceinline__ void gload_lds16(const void* g, void* l) {
  __builtin_amdgcn_global_load_lds(
      (const __attribute__((address_space(1))) void*)g,
      (__attribute__((address_space(3))) void*)l, 16, 0, 0);
}

__device__ __forceinline__ float tmax16(const f32x16& v) {
  float a0 = fmaxf(v[0], v[1]),   a1 = fmaxf(v[2], v[3]);
  float a2 = fmaxf(v[4], v[5]),   a3 = fmaxf(v[6], v[7]);
  float a4 = fmaxf(v[8], v[9]),   a5 = fmaxf(v[10], v[11]);
  float a6 = fmaxf(v[12], v[13]), a7 = fmaxf(v[14], v[15]);
  float b0 = fmaxf(a0, a1), b1 = fmaxf(a2, a3);
  float b2 = fmaxf(a4, a5), b3 = fmaxf(a6, a7);
  return fmaxf(fmaxf(b0, b1), fmaxf(b2, b3));
}
__device__ __forceinline__ float tsum16(const f32x16& v) {
  float a0 = v[0] + v[1],   a1 = v[2] + v[3];
  float a2 = v[4] + v[5],   a3 = v[6] + v[7];
  float a4 = v[8] + v[9],   a5 = v[10] + v[11];
  float a6 = v[12] + v[13], a7 = v[14] + v[15];
  float b0 = a0 + a1, b1 = a2 + a3, b2 = a4 + a5, b3 = a6 + a7;
  return (b0 + b1) + (b2 + b3);
}

#define MF(A, B, C) __builtin_amdgcn_mfma_f32_16x16x32_bf16((A), (B), (C), 0, 0, 0)

// ---- kernel 1: fused prep — VECTORIZED weight transpose + activation casts -
// wt path: 32(k) x 64(n) tiles; f4v loads (16B/lane), short4 stores (8B/lane).
struct PrepArgs { const float* W[6]; };

__global__ __launch_bounds__(256) void prep(PrepArgs a, short* __restrict__ wt,
                                            const float* __restrict__ hid,
                                            short* __restrict__ hbf, int n4h,
                                            const float* __restrict__ enc,
                                            short* __restrict__ ebf, int n4e) {
  __shared__ float t[32][65];
  int blk = blockIdx.x;
  if (blk < 3072) {
    // 512 blocks per W: tile = 32 k-rows (rb) x 64 n-cols (cb)
    int j = blk >> 9;
    int r = blk & 511;
    int rb = (r >> 4) * 32, cb = (r & 15) * 64;
    const float* W = a.W[j];
    short* dst = wt + (size_t)j * (HDIM * HDIM);
#pragma unroll
    for (int p = 0; p < 2; ++p) {
      int idx = p * 256 + threadIdx.x;
      int row = idx >> 4, c4 = idx & 15;
      f4v v = *(const f4v*)(&W[(size_t)(rb + row) * HDIM + cb + c4 * 4]);
      t[row][c4 * 4 + 0] = v[0];
      t[row][c4 * 4 + 1] = v[1];
      t[row][c4 * 4 + 2] = v[2];
      t[row][c4 * 4 + 3] = v[3];
    }
    __syncthreads();
#pragma unroll
    for (int p = 0; p < 2; ++p) {
      int idx = p * 256 + threadIdx.x;
      int rr = idx >> 3, ch = idx & 7;     // out row rr (n), 8 short4 chunks (k)
      s4v o;
#pragma unroll
      for (int q = 0; q < 4; ++q) o[q] = f2bf(t[ch * 4 + q][rr]);
      *(s4v*)(&dst[(size_t)(cb + rr) * HDIM + rb + ch * 4]) = o;
    }
  } else {
    int i = (blk - 3072) * 256 + threadIdx.x;
    const float* s;
    short* d;
    int j;
    if (i < n4h) { s = hid; d = hbf; j = i; }
    else { j = i - n4h; if (j >= n4e) return; s = enc; d = ebf; }
    f4v v = ((const f4v*)s)[j];
    s4v o;
#pragma unroll
    for (int k = 0; k < 4; ++k) o[k] = f2bf(v[k]);
    ((s4v*)d)[j] = o;
  }
}

// ---- kernel 3: projection GEMM (round-12 best: 75.5us) — FROZEN ------------
struct ProjArgs {
  const short* X[6];
  const short* Wt[6];
  const float* bias[6];
  short* out[6];
  int M[6];
  int tshift[6];
  int mode[6];
  float scale[6];
};

__global__ __launch_bounds__(256) void proj_gemm(ProjArgs a) {
  int job = blockIdx.z;
  int M = a.M[job];
  int by = blockIdx.y;
  if (by * 128 >= M) return;
  int bx = blockIdx.x;
  const short* X = a.X[job];
  const short* W = a.Wt[job];

  __shared__ __align__(16) char Lds[65536];   // 4 bufs x (A 8K | B 8K)

  int tid = threadIdx.x, lane = tid & 63, wave = tid >> 6;
  int wr = wave >> 1, wc = wave & 1;
  int l15 = lane & 15, g4 = lane >> 4;

  f32x4 acc[4][4];
#pragma unroll
  for (int m = 0; m < 4; ++m)
#pragma unroll
    for (int n = 0; n < 4; ++n)
#pragma unroll
      for (int r = 0; r < 4; ++r) acc[m][n][r] = 0.0f;

  int arow = by * 128, brow = bx * 128;
  const int crow = lane >> 2;
  const int sgrp = (lane & 3) ^ ((lane >> 2) & 3) ^ (lane >> 4);
  const int rsw = (lane & 3) ^ (l15 >> 2);

  const char* Xb = (const char*)X;
  const char* Wb = (const char*)W;
  const size_t sac0 = ((size_t)(arow + 32 * wave + crow) * HDIM + sgrp * 8) * 2;
  const size_t sac1 = sac0 + (size_t)16 * HDIM * 2;
  const size_t sbc0 = ((size_t)(brow + 32 * wave + crow) * HDIM + sgrp * 8) * 2;
  const size_t sbc1 = sbc0 + (size_t)16 * HDIM * 2;
  const int ldA0 = wave * 2048, ldA1 = ldA0 + 1024;
  const int ldB0 = 8192 + ldA0, ldB1 = ldB0 + 1024;

  const int aoff = wr * 4096 + l15 * 64 + ((g4 ^ rsw) << 4);
  const int boff = 8192 + wc * 4096 + l15 * 64 + ((g4 ^ rsw) << 4);

#define STG_A(SBO, SKT)                                                  \
  do {                                                                   \
    gload_lds16(Xb + sac0 + (size_t)(SKT) * 64, Lds + (SBO) + ldA0);     \
    gload_lds16(Xb + sac1 + (size_t)(SKT) * 64, Lds + (SBO) + ldA1);     \
  } while (0)
#define STG_B(SBO, SKT)                                                  \
  do {                                                                   \
    gload_lds16(Wb + sbc0 + (size_t)(SKT) * 64, Lds + (SBO) + ldB0);     \
    gload_lds16(Wb + sbc1 + (size_t)(SKT) * 64, Lds + (SBO) + ldB1);     \
  } while (0)

  // prologue: tiles 0,1,2 -> bufs 0,1,2; publish tiles 0,1.
  STG_A(0, 0);     STG_B(0, 0);
  STG_A(16384, 1); STG_B(16384, 1);
  STG_A(32768, 2); STG_B(32768, 2);
  asm volatile("s_waitcnt vmcnt(4)" ::: "memory");
  __builtin_amdgcn_s_barrier();
  asm volatile("" ::: "memory");

  bf16x8 xa0, xa1, xb0, xb1, xb2, xb3;
  bf16x8 ya0, ya1, yb0, yb1, yb2, yb3;

  xa0 = *(const bf16x8*)(Lds + 0 * 1024 + aoff);
  xa1 = *(const bf16x8*)(Lds + 1 * 1024 + aoff);
  xb0 = *(const bf16x8*)(Lds + 0 * 1024 + boff);
  xb1 = *(const bf16x8*)(Lds + 1 * 1024 + boff);
  xb2 = *(const bf16x8*)(Lds + 2 * 1024 + boff);
  xb3 = *(const bf16x8*)(Lds + 3 * 1024 + boff);

#define GSTEP_I(BO, BON, CA0, CA1, CB0, CB1, CB2, CB3, NA0, NA1, NB0, NB1,    \
                NB2, NB3, DO_STG, SBO, SKT, DO_NEXT, VMASM, DO_BAR)           \
  do {                                                                        \
    bf16x8 q2 = *(const bf16x8*)(Lds + (BO) + 2 * 1024 + aoff);               \
    bf16x8 q3 = *(const bf16x8*)(Lds + (BO) + 3 * 1024 + aoff);               \
    if (DO_STG) STG_A(SBO, SKT);                                              \
    __builtin_amdgcn_s_setprio(1);                                            \
    acc[0][0] = MF(CA0, CB0, acc[0][0]);                                      \
    acc[0][1] = MF(CA0, CB1, acc[0][1]);                                      \
    acc[0][2] = MF(CA0, CB2, acc[0][2]);                                      \
    acc[0][3] = MF(CA0, CB3, acc[0][3]);                                      \
    acc[1][0] = MF(CA1, CB0, acc[1][0]);                                      \
    acc[1][1] = MF(CA1, CB1, acc[1][1]);                                      \
    acc[1][2] = MF(CA1, CB2, acc[1][2]);                                      \
    acc[1][3] = MF(CA1, CB3, acc[1][3]);                                      \
    __builtin_amdgcn_s_setprio(0);                                            \
    if (DO_NEXT) {                                                            \
      NA0 = *(const bf16x8*)(Lds + (BON) + 0 * 1024 + aoff);                  \
      NA1 = *(const bf16x8*)(Lds + (BON) + 1 * 1024 + aoff);                  \
      NB0 = *(const bf16x8*)(Lds + (BON) + 0 * 1024 + boff);                  \
      NB1 = *(const bf16x8*)(Lds + (BON) + 1 * 1024 + boff);                  \
      NB2 = *(const bf16x8*)(Lds + (BON) + 2 * 1024 + boff);                  \
      NB3 = *(const bf16x8*)(Lds + (BON) + 3 * 1024 + boff);                  \
    }                                                                         \
    if (DO_STG) STG_B(SBO, SKT);                                              \
    __builtin_amdgcn_s_setprio(1);                                            \
    acc[2][0] = MF(q2, CB0, acc[2][0]);                                       \
    acc[2][1] = MF(q2, CB1, acc[2][1]);                                       \
    acc[2][2] = MF(q2, CB2, acc[2][2]);                                       \
    acc[2][3] = MF(q2, CB3, acc[2][3]);                                       \
    acc[3][0] = MF(q3, CB0, acc[3][0]);                                       \
    acc[3][1] = MF(q3, CB1, acc[3][1]);                                       \
    acc[3][2] = MF(q3, CB2, acc[3][2]);                                       \
    acc[3][3] = MF(q3, CB3, acc[3][3]);                                       \
    __builtin_amdgcn_s_setprio(0);                                            \
    asm volatile(VMASM ::: "memory");                                         \
    if (DO_BAR) {                                                             \
      __builtin_amdgcn_s_barrier();                                           \
      asm volatile("" ::: "memory");                                          \
    }                                                                         \
  } while (0)
#define GSTEP(...) GSTEP_I(__VA_ARGS__)

#define XSET xa0, xa1, xb0, xb1, xb2, xb3
#define YSET ya0, ya1, yb0, yb1, yb2, yb3

#pragma unroll 1
  for (int it = 0; it < 7; ++it) {
    int t0 = it * 4;
    GSTEP(0,     16384, XSET, YSET, 1, 49152, t0 + 3, 1, "s_waitcnt vmcnt(4)", 1);
    GSTEP(16384, 32768, YSET, XSET, 1, 0,     t0 + 4, 1, "s_waitcnt vmcnt(4)", 1);
    GSTEP(32768, 49152, XSET, YSET, 1, 16384, t0 + 5, 1, "s_waitcnt vmcnt(4)", 1);
    GSTEP(49152, 0,     YSET, XSET, 1, 32768, t0 + 6, 1, "s_waitcnt vmcnt(4)", 1);
  }
  GSTEP(0,     16384, XSET, YSET, 1, 49152, 31, 1, "s_waitcnt vmcnt(4)", 1);
  GSTEP(16384, 32768, YSET, XSET, 0, 0, 0,      1, "s_waitcnt vmcnt(0)", 1);
  GSTEP(32768, 49152, XSET, YSET, 0, 0, 0,      1, "s_nop 0", 1);
  GSTEP(49152, 0,     YSET, XSET, 0, 0, 0,      0, "s_nop 0", 0);

#undef GSTEP
#undef GSTEP_I
#undef XSET
#undef YSET
#undef STG_A
#undef STG_B

  const float* bias = a.bias[job];
  short* out = a.out[job];
  int tshift = a.tshift[job], tmask = (1 << tshift) - 1, mode = a.mode[job];
  float scl = a.scale[job];
#pragma unroll
  for (int m = 0; m < 4; ++m) {
    int rowb = arow + wr * 64 + m * 16 + (g4 << 2);
#pragma unroll
    for (int n = 0; n < 4; ++n) {
      int col = brow + wc * 64 + n * 16 + l15;
      float bv = bias[col];
      int head = col >> 6, d = col & 63;
#pragma unroll
      for (int r = 0; r < 4; ++r) {
        int row = rowb + r;
        int bb = row >> tshift, tk = row & tmask;
        float val = (acc[m][n][r] + bv) * scl;
        size_t idx;
        if (mode == 0)
          idx = ((((size_t)bb * NHEAD + head) << tshift) + tk) * 64 + d;
        else
          idx = ((((size_t)bb * NHEAD + head) * 64 + d) << tshift) + tk;
        out[idx] = f2bf(val);
      }
    }
  }
}

// ---- kernel 4: swapped-QK^T 32x32 flash attention (r13 version) ------------
__global__ __launch_bounds__(128, 2) void attn32(
    const short* __restrict__ qall, const short* __restrict__ kall,
    const short* __restrict__ vTall, const short* __restrict__ kqall,
    const short* __restrict__ kkall, const short* __restrict__ kvTall,
    const float* __restrict__ amask, const float* __restrict__ emask,
    float* __restrict__ out) {
  __shared__ char KT[2][8192];
  __shared__ char VT[2][8192];
  __shared__ float red[2][32];

  int lid = blockIdx.x;
  int id = (lid & 7) * 128 + (lid >> 3);
  int bh = id >> 4, qb = id & 15;
  int b = bh >> 4, h = bh & 15;
  int lane = threadIdx.x & 63, wave = threadIdx.x >> 6;
  int l31 = lane & 31, hi = lane >> 5, x7 = l31 & 7;
  int qrow0 = qb * 64 + wave * 32;

  bf16x8 qcur[4];
  {
    const short* qp = qall + ((size_t)bh * SEQ + qrow0 + l31) * 64;
#pragma unroll
    for (int i = 0; i < 4; ++i)
      qcur[i] = *(const bf16x8*)(qp + i * 16 + hi * 8);
  }

  const char* kb0 = (const char*)(kall + (size_t)bh * SEQ * 64);
  const char* vb0 = (const char*)(vTall + (size_t)bh * 64 * SEQ);
  const char* kb1 = (const char*)(kkall + (size_t)bh * KENC * 64);
  const char* vb1 = (const char*)(kvTall + (size_t)bh * 64 * KENC);
  const float* mpc = amask + (size_t)b * SEQ;

  auto STAGE = [&](int pb, const char* kb, const char* vb, size_t vrowb, int kt) {
    int t0 = threadIdx.x;
#pragma unroll
    for (int c = 0; c < 4; ++c) {
      int idx = c * 128 + t0;
      int row = idx >> 3, phys = idx & 7;
      int lg = phys ^ (row & 7);
      gload_lds16(kb + ((size_t)(kt * 64 + row)) * 128 + lg * 16,
                  KT[pb] + idx * 16);
      gload_lds16(vb + (size_t)row * vrowb + (size_t)kt * 128 + lg * 16,
                  VT[pb] + idx * 16);
    }
  };

  STAGE(0, kb0, vb0, SEQ * 2, 0);

  f32x16 ctx0, ctx1, c10, c11;
#pragma unroll
  for (int r = 0; r < 16; ++r) { ctx0[r] = 0.f; ctx1[r] = 0.f; c10[r] = 0.f; c11[r] = 0.f; }
  float mr = -1e30f, lr = 0.f;

#pragma unroll 1
  for (int t = 0; t < 24; ++t) {
    int p = t & 1;
    __syncthreads();
    if (t < 23) {
      int tn = t + 1;
      if (tn >= 16) STAGE(p ^ 1, kb1, vb1, KENC * 2, tn - 16);
      else          STAGE(p ^ 1, kb0, vb0, SEQ * 2, tn);
    }
    if (t == 16) {
      if (!hi) red[wave][l31] = lr;
      asm volatile("s_waitcnt lgkmcnt(0)" ::: "memory");
#pragma unroll
      for (int r2 = 0; r2 < 4; ++r2) {
        f4v lv = *(const f4v*)(&red[wave][r2 * 8 + 4 * hi]);
#pragma unroll
        for (int j2 = 0; j2 < 4; ++j2) {
          float li = __builtin_amdgcn_rcpf(lv[j2]);
          int r = r2 * 4 + j2;
          c10[r] = ctx0[r] * li;  ctx0[r] = 0.f;
          c11[r] = ctx1[r] * li;  ctx1[r] = 0.f;
        }
      }
      mr = -1e30f; lr = 0.f;
      const short* kqp = kqall + ((size_t)bh * SEQ + qrow0 + l31) * 64;
#pragma unroll
      for (int i = 0; i < 4; ++i)
        qcur[i] = *(const bf16x8*)(kqp + i * 16 + hi * 8);
      mpc = emask + (size_t)b * KENC;
    }
    int kt = (t >= 16) ? t - 16 : t;
    const char* Kp = KT[p];
    const char* Vp = VT[p];

    f32x16 s0, s1;
#pragma unroll
    for (int r = 0; r < 16; ++r) { s0[r] = 0.f; s1[r] = 0.f; }
    __builtin_amdgcn_s_setprio(1);
#pragma unroll
    for (int i = 0; i < 4; ++i) {
      bf16x8 kf = *(const bf16x8*)(Kp + (l31)*128 + (((2 * i + hi) ^ x7) << 4));
      s0 = __builtin_amdgcn_mfma_f32_32x32x16_bf16(kf, qcur[i], s0, 0, 0, 0);
    }
#pragma unroll
    for (int i = 0; i < 4; ++i) {
      bf16x8 kf = *(const bf16x8*)(Kp + (32 + l31) * 128 + (((2 * i + hi) ^ x7) << 4));
      s1 = __builtin_amdgcn_mfma_f32_32x32x16_bf16(kf, qcur[i], s1, 0, 0, 0);
    }
    __builtin_amdgcn_s_setprio(0);

    const float* mp = mpc + kt * 64;
#pragma unroll
    for (int r2 = 0; r2 < 4; ++r2) {
      f4v ma = *(const f4v*)(mp + r2 * 8 + 4 * hi);
      f4v mb = *(const f4v*)(mp + 32 + r2 * 8 + 4 * hi);
#pragma unroll
      for (int j2 = 0; j2 < 4; ++j2) {
        s0[r2 * 4 + j2] = fmaf(ma[j2], LOG2E, s0[r2 * 4 + j2]);
        s1[r2 * 4 + j2] = fmaf(mb[j2], LOG2E, s1[r2 * 4 + j2]);
      }
    }

    float mx = fmaxf(tmax16(s0), tmax16(s1));
    mx = fmaxf(mx, __int_as_float(__shfl_xor(__float_as_int(mx), 32)));

    if (!__all(mx <= mr + 12.f)) {
      float mn = fmaxf(mr, mx);
      float scl = __builtin_amdgcn_exp2f(mr - mn);
      mr = mn; lr *= scl;
      if (!hi) red[wave][l31] = scl;
      asm volatile("s_waitcnt lgkmcnt(0)" ::: "memory");
#pragma unroll
      for (int r2 = 0; r2 < 4; ++r2) {
        f4v sv = *(const f4v*)(&red[wave][r2 * 8 + 4 * hi]);
#pragma unroll
        for (int j2 = 0; j2 < 4; ++j2) {
          ctx0[r2 * 4 + j2] *= sv[j2];
          ctx1[r2 * 4 + j2] *= sv[j2];
        }
      }
    }

#pragma unroll
    for (int r = 0; r < 16; ++r) s0[r] = __builtin_amdgcn_exp2f(s0[r] - mr);
#pragma unroll
    for (int r = 0; r < 16; ++r) s1[r] = __builtin_amdgcn_exp2f(s1[r] - mr);
    float rs = tsum16(s0) + tsum16(s1);
    rs += __int_as_float(__shfl_xor(__float_as_int(rs), 32));
    lr += rs;

#pragma unroll
    for (int s = 0; s < 2; ++s) {
      const f32x16& sv = s ? s1 : s0;
      unsigned W[8];
#pragma unroll
      for (int r2 = 0; r2 < 4; ++r2) {
        asm("v_cvt_pk_bf16_f32 %0, %1, %2"
            : "=v"(W[r2 * 2]) : "v"(sv[r2 * 4 + 0]), "v"(sv[r2 * 4 + 1]));
        asm("v_cvt_pk_bf16_f32 %0, %1, %2"
            : "=v"(W[r2 * 2 + 1]) : "v"(sv[r2 * 4 + 2]), "v"(sv[r2 * 4 + 3]));
      }
#pragma unroll
      for (int jr = 0; jr < 2; ++jr) {
        unsigned sendA = hi ? W[(2 * jr) * 2]     : W[(2 * jr + 1) * 2];
        unsigned sendB = hi ? W[(2 * jr) * 2 + 1] : W[(2 * jr + 1) * 2 + 1];
        unsigned rA = (unsigned)__shfl_xor((int)sendA, 32);
        unsigned rB = (unsigned)__shfl_xor((int)sendB, 32);
        union { unsigned u[4]; bf16x8 v; } pa;
        if (!hi) { pa.u[0] = W[2 * jr * 2]; pa.u[1] = W[2 * jr * 2 + 1];
                   pa.u[2] = rA;            pa.u[3] = rB; }
        else     { pa.u[0] = rA;            pa.u[1] = rB;
                   pa.u[2] = W[(2 * jr + 1) * 2]; pa.u[3] = W[(2 * jr + 1) * 2 + 1]; }
        int j = s * 2 + jr;
        __builtin_amdgcn_s_setprio(1);
        bf16x8 vf0 = *(const bf16x8*)(Vp + (l31)*128 + (((2 * j + hi) ^ x7) << 4));
        ctx0 = __builtin_amdgcn_mfma_f32_32x32x16_bf16(pa.v, vf0, ctx0, 0, 0, 0);
        bf16x8 vf1 = *(const bf16x8*)(Vp + (32 + l31) * 128 + (((2 * j + hi) ^ x7) << 4));
        ctx1 = __builtin_amdgcn_mfma_f32_32x32x16_bf16(pa.v, vf1, ctx1, 0, 0, 0);
        __builtin_amdgcn_s_setprio(0);
      }
    }
  }

  if (!hi) red[wave][l31] = lr;
  asm volatile("s_waitcnt lgkmcnt(0)" ::: "memory");
  float* op = out + ((size_t)b * SEQ) * HDIM + h * 64 + l31;
#pragma unroll
  for (int r2 = 0; r2 < 4; ++r2) {
    f4v lv = *(const f4v*)(&red[wave][r2 * 8 + 4 * hi]);
#pragma unroll
    for (int j2 = 0; j2 < 4; ++j2) {
      float li = __builtin_amdgcn_rcpf(lv[j2]);
      int s = qrow0 + r2 * 8 + 4 * hi + j2;
      int r = r2 * 4 + j2;
      op[(size_t)s * HDIM]      = 0.5f * (c10[r] + ctx0[r] * li);
      op[(size_t)s * HDIM + 32] = 0.5f * (c11[r] + ctx1[r] * li);
    }
  }
}

// ---- host launcher ---------------------------------------------------------
extern "C" void kernel_launch(void* const* d_in, const int* in_sizes, int n_in,
                              void* d_out, int out_size, void* d_ws, size_t ws_size,
                              hipStream_t stream) {
  const float* hid = (const float*)d_in[0];
  const float* enc = (const float*)d_in[1];
  const float* amask = (const float*)d_in[2];
  const float* emask = (const float*)d_in[3];

  char* ws = (char*)d_ws;
  short* hbf = (short*)(ws);                        // 8 MB  [B*S,H] bf16
  short* ebf = (short*)(ws + (8u << 20));           // 4 MB  [B*K,H]
  short* wt = (short*)(ws + (12u << 20));           // 12 MB 6x [n][k]
  short* qo = (short*)(ws + (24u << 20));           // 8 MB  [B,NH,S,HD]
  short* ko = (short*)(ws + (32u << 20));           // 8 MB
  short* vT = (short*)(ws + (40u << 20));           // 8 MB  [B,NH,HD,S]
  short* kqo = (short*)(ws + (48u << 20));          // 8 MB
  short* kko = (short*)(ws + (56u << 20));          // 4 MB  [B,NH,K,HD]
  short* kvT = (short*)(ws + (60u << 20));          // 4 MB  [B,NH,HD,K]

  PrepArgs wa;
  for (int j = 0; j < 6; ++j) wa.W[j] = (const float*)d_in[4 + 2 * j];
  prep<<<9216, 256, 0, stream>>>(wa, wt, hid, hbf, (BATCH * SEQ * HDIM) / 4,
                                 enc, ebf, (BATCH * KENC * HDIM) / 4);

  ProjArgs pa;
  const short* Xs[6] = {hbf, hbf, hbf, hbf, ebf, ebf};
  short* outs[6] = {qo, ko, vT, kqo, kko, kvT};
  const int Ms[6] = {4096, 4096, 4096, 4096, 2048, 2048};
  const int tsh[6] = {10, 10, 10, 10, 9, 9};
  const int md[6] = {0, 0, 1, 0, 0, 1};
  const float qscale = 0.125f * LOG2E;
  const float scl[6] = {qscale, 1.f, 1.f, qscale, 1.f, 1.f};
  for (int j = 0; j < 6; ++j) {
    pa.X[j] = Xs[j];
    pa.Wt[j] = wt + (size_t)j * (HDIM * HDIM);
    pa.bias[j] = (const float*)d_in[5 + 2 * j];
    pa.out[j] = outs[j];
    pa.M[j] = Ms[j];
    pa.tshift[j] = tsh[j];
    pa.mode[j] = md[j];
    pa.scale[j] = scl[j];
  }
  proj_gemm<<<dim3(8, 32, 6), 256, 0, stream>>>(pa);

  attn32<<<1024, 128, 0, stream>>>(qo, ko, vT, kqo, kko, kvT, amask, emask,
                                   (float*)d_out);
}